// Round 12
// baseline (232.081 us; speedup 1.0000x reference)
//
#include <hip/hip_runtime.h>

#define NG 16
#define NC 4
#define BPB 16     // batch items per block
#define TSTEPS 8
#define PITCH 64   // float4 per (c,y) row: 16 x * 4 quad-slots (swizzled)
#define CROW (NG * PITCH)   // 1024 float4 per channel

__device__ __forceinline__ void fma4(float w, const float4& s, float4& a) {
    a.x = fmaf(w, s.x, a.x);
    a.y = fmaf(w, s.y, a.y);
    a.z = fmaf(w, s.z, a.z);
    a.w = fmaf(w, s.w, a.w);
}

__device__ __forceinline__ float4 lrelu4(float4 v) {
    float4 r;
    r.x = fmaxf(v.x, 0.1f * v.x);
    r.y = fmaxf(v.y, 0.1f * v.y);
    r.z = fmaxf(v.z, 0.1f * v.z);
    r.w = fmaxf(v.w, 0.1f * v.w);
    return r;
}

// DPP row shift within 16-lane rows; bound_ctrl=1 zero-fills at row edges
// (matches reference zero padding; OOB weights pre-zeroed anyway).
// 0x111/0x112 = row_shr:1/2 (tap x-1/x-2); 0x101/0x102 = row_shl:1/2 (x+1/x+2).
template<int CTRL>
__device__ __forceinline__ float dppf(float x) {
    return __int_as_float(__builtin_amdgcn_update_dpp(
        0, __float_as_int(x), CTRL, 0xF, 0xF, true));
}
template<int CTRL>
__device__ __forceinline__ float4 dpp4(float4 v) {
    float4 r;
    r.x = dppf<CTRL>(v.x);
    r.y = dppf<CTRL>(v.y);
    r.z = dppf<CTRL>(v.z);
    r.w = dppf<CTRL>(v.w);
    return r;
}

// Wt[(c*25+u*5+v)*256 + pix] : float4 over o, OOB (u,v) pre-zeroed.
// Original W: [y][x][o][c][u][v] (flat: pix*400 + o*100 + c*25 + u*5 + v)
__global__ void wt_transpose(const float* __restrict__ W, float4* __restrict__ Wt) {
    int t = blockIdx.x * 256 + threadIdx.x;   // 0..25599
    if (t >= 25600) return;
    int r = t >> 8;            // c*25 + u*5 + v
    int pix = t & 255;
    int c = r / 25, uv = r - c * 25, u = uv / 5, v = uv - u * 5;
    int y = pix >> 4, x = pix & 15;
    float4 w = make_float4(0.f, 0.f, 0.f, 0.f);
    if ((unsigned)(y + u - 2) < 16u && (unsigned)(x + v - 2) < 16u) {
        int base = pix * 400 + c * 25 + uv;
        w.x = W[base];
        w.y = W[base + 100];
        w.z = W[base + 200];
        w.w = W[base + 300];
    }
    Wt[r * 256 + pix] = w;
}

// 512 threads = 2 batch-octs x 256 pixels (tid = oct*256 + pix); each wave is
// 64 consecutive pixels of one oct -> DPP geometry unchanged. Each thread:
// 4 o-channels x 8 items (2 quads) -> acc 8 float4 (32 VGPR); per (c,u) chunk
// 2 ds_read_b128 + DPP taps. 64 KiB LDS -> 2 blocks/CU -> 4 waves/SIMD (2x
// R11's TLP). Weights single-buffered with TAP-MAJOR RELOAD: consume tap v
// across both quads, then immediately reload w_v from the next chunk -- the
// anti-dependency pins the load after its last use (zero VGPR cost) and the
// next use is a full chunk (~640 cyc) away -> L2 latency hidden by
// construction. Runtime c/u loops fence cross-chunk hoisting (R4/R8-proven).
__global__ __launch_bounds__(512, 4)
void reservoir_kernel(const float* __restrict__ X, const float4* __restrict__ Wt,
                      float* __restrict__ out, int batch) {
    __shared__ float4 smv[NC * CROW];   // 65536 B
    float* smf = reinterpret_cast<float*>(smv);

    const int tid = threadIdx.x;
    const int oct = tid >> 8;           // 0: items 0-7, 1: items 8-15
    const int pix = tid & 255;
    const int y = pix >> 4;
    const int x = pix & 15;
    const long itemBase = (long)blockIdx.x * BPB;

    const int sw = (x >> 1) & 3;        // quad-slot swizzle
    const int xb = x << 2;
    const int q0 = (2 * oct) ^ sw;      // phys slot of quad 2*oct
    const int q1 = (2 * oct + 1) ^ sw;  // phys slot of quad 2*oct+1

    // ---- init: X (first 784 of 1024 slots) -> LDS ----
    for (int b = 0; b < BPB; ++b) {
        long item = itemBase + b;
        #pragma unroll
        for (int k = 0; k < 2; ++k) {
            int idx = tid + k * 512;    // 0..1023
            float v = 0.f;
            if (idx < 784 && item < batch)
                v = __builtin_nontemporal_load(&X[item * 784 + idx]);
            int c = idx >> 8, rem = idx & 255, yy = rem >> 4, xx = rem & 15;
            int phys = (b >> 2) ^ ((xx >> 1) & 3);
            smf[(((c * NG + yy) << 6) + (xx << 2) + phys) * 4 + (b & 3)] = v;
        }
    }

    // ---- weights: single-buffered 5 x float4, chunk 0 preloaded ----
    const float4* Wp = Wt + pix;
    float4 w0 = Wp[0], w1 = Wp[256], w2 = Wp[512], w3 = Wp[768], w4 = Wp[1024];
    int wnext = 1280;    // f4 offset of next chunk (chunk k at k*1280)

    __syncthreads();

    // one tap across both quads: 32 v_fma
#define TAP(WV, T0, T1) \
    fma4(WV.x, T0, a00); fma4(WV.x, T1, a01); \
    fma4(WV.y, T0, a10); fma4(WV.y, T1, a11); \
    fma4(WV.z, T0, a20); fma4(WV.z, T1, a21); \
    fma4(WV.w, T0, a30); fma4(WV.w, T1, a31);

    #pragma unroll 1
    for (int t = 0; t < TSTEPS; ++t) {
        float4 a00 = {0,0,0,0}, a01 = {0,0,0,0};
        float4 a10 = {0,0,0,0}, a11 = {0,0,0,0};
        float4 a20 = {0,0,0,0}, a21 = {0,0,0,0};
        float4 a30 = {0,0,0,0}, a31 = {0,0,0,0};

        #pragma unroll 1
        for (int c = 0; c < NC; ++c) {
            #pragma unroll 1
            for (int u = 0; u < 5; ++u) {
                int yy = y + u - 2;
                yy = yy < 0 ? 0 : (yy > 15 ? 15 : yy);   // OOB rows: w pre-zeroed
                const int rb = ((c * NG + yy) << 6) + xb;
                const float4 s0 = smv[rb + q0];
                const float4 s1 = smv[rb + q1];

                // tap-major: consume w_v on both quads, then reload w_v
                TAP(w2, s0, s1)
                w2 = Wp[wnext + 512];
                { const float4 t0 = dpp4<0x111>(s0), t1 = dpp4<0x111>(s1);  // x-1
                  TAP(w1, t0, t1) }
                w1 = Wp[wnext + 256];
                { const float4 t0 = dpp4<0x101>(s0), t1 = dpp4<0x101>(s1);  // x+1
                  TAP(w3, t0, t1) }
                w3 = Wp[wnext + 768];
                { const float4 t0 = dpp4<0x112>(s0), t1 = dpp4<0x112>(s1);  // x-2
                  TAP(w0, t0, t1) }
                w0 = Wp[wnext];
                { const float4 t0 = dpp4<0x102>(s0), t1 = dpp4<0x102>(s1);  // x+2
                  TAP(w4, t0, t1) }
                w4 = Wp[wnext + 1024];

                wnext += 1280;
                if (wnext >= 25600) wnext = 0;   // chunk 19 -> chunk 0
            }
        }

        a00 = lrelu4(a00); a01 = lrelu4(a01);
        a10 = lrelu4(a10); a11 = lrelu4(a11);
        a20 = lrelu4(a20); a21 = lrelu4(a21);
        a30 = lrelu4(a30); a31 = lrelu4(a31);

        if (t < TSTEPS - 1) {
            __syncthreads();   // all reads of S[t] complete before overwrite
            const int pb = (y << 6) + xb;
            smv[0 * CROW + pb + q0] = a00;  smv[0 * CROW + pb + q1] = a01;
            smv[1 * CROW + pb + q0] = a10;  smv[1 * CROW + pb + q1] = a11;
            smv[2 * CROW + pb + q0] = a20;  smv[2 * CROW + pb + q1] = a21;
            smv[3 * CROW + pb + q0] = a30;  smv[3 * CROW + pb + q1] = a31;
            __syncthreads();   // writes visible before next read phase
        } else {
            // channel-mean: p0 = items 8*oct..+3, p1 = +4..+7
            float4 p0, p1;
            p0.x = (a00.x + a10.x + a20.x + a30.x) * 0.25f;
            p0.y = (a00.y + a10.y + a20.y + a30.y) * 0.25f;
            p0.z = (a00.z + a10.z + a20.z + a30.z) * 0.25f;
            p0.w = (a00.w + a10.w + a20.w + a30.w) * 0.25f;
            p1.x = (a01.x + a11.x + a21.x + a31.x) * 0.25f;
            p1.y = (a01.y + a11.y + a21.y + a31.y) * 0.25f;
            p1.z = (a01.z + a11.z + a21.z + a31.z) * 0.25f;
            p1.w = (a01.w + a11.w + a21.w + a31.w) * 0.25f;
            const long b0 = itemBase + 8 * oct;
            const long ob = b0 * 256 + pix;
            if (b0 + 0 < batch) __builtin_nontemporal_store(p0.x, &out[ob + 0 * 256]);
            if (b0 + 1 < batch) __builtin_nontemporal_store(p0.y, &out[ob + 1 * 256]);
            if (b0 + 2 < batch) __builtin_nontemporal_store(p0.z, &out[ob + 2 * 256]);
            if (b0 + 3 < batch) __builtin_nontemporal_store(p0.w, &out[ob + 3 * 256]);
            if (b0 + 4 < batch) __builtin_nontemporal_store(p1.x, &out[ob + 4 * 256]);
            if (b0 + 5 < batch) __builtin_nontemporal_store(p1.y, &out[ob + 5 * 256]);
            if (b0 + 6 < batch) __builtin_nontemporal_store(p1.z, &out[ob + 6 * 256]);
            if (b0 + 7 < batch) __builtin_nontemporal_store(p1.w, &out[ob + 7 * 256]);
        }
    }
}

extern "C" void kernel_launch(void* const* d_in, const int* in_sizes, int n_in,
                              void* d_out, int out_size, void* d_ws, size_t ws_size,
                              hipStream_t stream) {
    const float* X = (const float*)d_in[0];
    const float* W = (const float*)d_in[1];
    float* out = (float*)d_out;
    const int batch = in_sizes[0] / 784;            // 8192
    const int blocks = (batch + BPB - 1) / BPB;     // 512

    wt_transpose<<<100, 256, 0, stream>>>(W, (float4*)d_ws);
    reservoir_kernel<<<blocks, 512, 0, stream>>>(
        X, (const float4*)d_ws, out, batch);
}